// Round 10
// baseline (169.299 us; speedup 1.0000x reference)
//
#include <hip/hip_runtime.h>
#include <math.h>

#define D_MODEL 768
#define HS 64
#define BATCH 8
#define SEQ 2048
// Q is pre-scaled by 0.125*log2(e) in proj's epilogue (fp32), so attn
// computes P = 2^(Qs . K) with a single v_exp_f32 and no extra muls.
#define QSCALE_LOG2E 0.1803368801f
#define KSPLIT 16
#define KCHUNK (SEQ / KSPLIT)   // 128
#define PM 32                   // proj M-tile -> grid 512

typedef _Float16 half_t;
typedef __attribute__((ext_vector_type(8))) _Float16 half8;
typedef __attribute__((ext_vector_type(4))) float floatx4;

// async global->LDS, 16B per lane, lane-linear LDS destination
typedef const __attribute__((address_space(1))) void gas_void;
typedef __attribute__((address_space(3))) void las_void;
__device__ __forceinline__ void gl_lds16(const void* g, void* l) {
    __builtin_amdgcn_global_load_lds((gas_void*)g, (las_void*)l, 16, 0, 0);
}
__device__ __forceinline__ void waitcnt_all() {
    __builtin_amdgcn_s_waitcnt(0);
}
__device__ __forceinline__ float fast_exp2(float x) {
#if __has_builtin(__builtin_amdgcn_exp2f)
    return __builtin_amdgcn_exp2f(x);
#else
    return exp2f(x);
#endif
}

// ---------------------------------------------------------------
// Kernel 1: W fp32 [D][H] x3 -> Wt fp16 [3*H][D], via coalesced
// 64x64 LDS transpose. Grid 36 = 3 matrices x 12 k-tiles.
// ---------------------------------------------------------------
__global__ __launch_bounds__(256)
void wconv_kernel(const float* __restrict__ Wq, const float* __restrict__ Wk,
                  const float* __restrict__ Wv, half_t* __restrict__ Wt)
{
    __shared__ float lds[64][65];
    const int m = blockIdx.x / 12;
    const int k0 = (blockIdx.x % 12) * 64;
    const float* W = (m == 0) ? Wq : ((m == 1) ? Wk : Wv);
    const int tid = threadIdx.x;
#pragma unroll
    for (int ri = 0; ri < 4; ++ri) {
        int row = ri * 16 + (tid >> 4);
        int col = (tid & 15) * 4;
        float4 v = *(const float4*)(W + (size_t)(k0 + row) * HS + col);
        lds[row][col] = v.x; lds[row][col + 1] = v.y;
        lds[row][col + 2] = v.z; lds[row][col + 3] = v.w;
    }
    __syncthreads();
#pragma unroll
    for (int i = 0; i < 2; ++i) {
        int idx = i * 256 + tid;
        int h = idx >> 3;
        int kc = idx & 7;
        half8 o;
#pragma unroll
        for (int j = 0; j < 8; ++j) o[j] = (half_t)lds[kc * 8 + j][h];
        *(half8*)(Wt + (size_t)(m * HS + h) * D_MODEL + k0 + kc * 8) = o;
    }
}

// ---------------------------------------------------------------
// Kernel 2: QKV projection (R9, unchanged). M=32 x N=192 tile,
// parity dbuf LDS, W staging via global_load_lds.
// ---------------------------------------------------------------
__global__ __launch_bounds__(256)
void proj_kernel(const float* __restrict__ x, const half_t* __restrict__ Wt,
                 const float* __restrict__ bq, const float* __restrict__ bk,
                 const float* __restrict__ bv,
                 half_t* __restrict__ Qh, half_t* __restrict__ Kh,
                 half_t* __restrict__ Vt)
{
    __shared__ __align__(16) half_t xs[2][PM * 64];    // 2 x 4 KB
    __shared__ __align__(16) half_t wtl[2][192 * 64];  // 2 x 24 KB

    const int tid = threadIdx.x;
    const int w = tid >> 6;
    const int lane = tid & 63;
    const int l15 = lane & 15;
    const int quad = lane >> 4;
    const long row0 = (long)blockIdx.x * PM;

    floatx4 acc[2][3];
#pragma unroll
    for (int i = 0; i < 2; ++i)
#pragma unroll
        for (int j = 0; j < 3; ++j) acc[i][j] = (floatx4){0.f, 0.f, 0.f, 0.f};

    float4 xA[2], xB[2];

    auto loadx = [&](int k0, float4 (&v)[2]) {
        int r = tid >> 3, sc = tid & 7;
        int cg = sc ^ (r & 7);
        const float* p = x + (row0 + r) * D_MODEL + k0 + cg * 8;
        v[0] = *(const float4*)p;
        v[1] = *(const float4*)(p + 4);
    };
    // async W stage: same global pre-swizzle, lane-linear LDS dest
    auto stage_w = [&](int p, int k0) {
#pragma unroll
        for (int i = 0; i < 6; ++i) {
            int idx = i * 256 + tid;
            int r = idx >> 3, sc = idx & 7;
            int cg = sc ^ (r & 7);
            gl_lds16(Wt + (size_t)r * D_MODEL + k0 + cg * 8, &wtl[p][idx * 8]);
        }
    };

    auto step = [&](int it, float4 (&xc)[2], float4 (&xn)[2], int p) {
        {
            float4 a = xc[0], b = xc[1];
            half8 xh = (half8){(half_t)a.x, (half_t)a.y, (half_t)a.z, (half_t)a.w,
                               (half_t)b.x, (half_t)b.y, (half_t)b.z, (half_t)b.w};
            *(half8*)&xs[p][tid * 8] = xh;
        }
        waitcnt_all();                   // this wave's W gl_lds (tile it) landed
        __syncthreads();                 // xs[p]+wtl[p] visible to all waves
        int kn = (it + 1 < 12) ? (it + 1) * 64 : 0;
        if (it + 1 < 12) stage_w(p ^ 1, kn);
        loadx(kn, xn);
#pragma unroll
        for (int kst = 0; kst < 2; ++kst) {
            half8 af[2];
#pragma unroll
            for (int mt = 0; mt < 2; ++mt) {
                int r = mt * 16 + l15;
                int slot = (kst * 4 + quad) ^ (r & 7);
                af[mt] = *(const half8*)&xs[p][r * 64 + slot * 8];
            }
#pragma unroll
            for (int nt = 0; nt < 3; ++nt) {
                int r = w * 48 + nt * 16 + l15;
                int slot = (kst * 4 + quad) ^ (r & 7);
                half8 bf = *(const half8*)&wtl[p][r * 64 + slot * 8];
#pragma unroll
                for (int mt = 0; mt < 2; ++mt)
                    acc[mt][nt] = __builtin_amdgcn_mfma_f32_16x16x32_f16(
                        af[mt], bf, acc[mt][nt], 0, 0, 0);
            }
        }
    };

    stage_w(0, 0);                       // W tile 0 in flight
    loadx(0, xA);
#pragma unroll
    for (int it = 0; it < 12; it += 2) {
        step(it,     xA, xB, 0);
        step(it + 1, xB, xA, 1);
    }

    // epilogue: bias (+ Q pre-scale) + fp16 store
#pragma unroll
    for (int nt = 0; nt < 3; ++nt) {
        int nbase = w * 48 + nt * 16;
        int mm = nbase >> 6;
        int h = (nbase + l15) & 63;
        const float* bias = (mm == 0) ? bq : ((mm == 1) ? bk : bv);
        float bval = bias[h];
#pragma unroll
        for (int mt = 0; mt < 2; ++mt)
#pragma unroll
            for (int r = 0; r < 4; ++r) {
                long R = row0 + mt * 16 + quad * 4 + r;
                float fv = acc[mt][nt][r] + bval;
                if (mm == 0) {
                    Qh[R * HS + h] = (half_t)(fv * QSCALE_LOG2E);
                } else if (mm == 1) {
                    Kh[R * HS + h] = (half_t)fv;
                } else {
                    long bb = R >> 11, s = R & 2047;
                    Vt[(bb * HS + h) * SEQ + s] = (half_t)fv;
                }
            }
    }
}

// ---------------------------------------------------------------
// Kernel 3: flash attention. Interior identical to R8. Changes:
//  - KSPLIT 16: grid 2048 (was 1024 = 4 blocks/CU = 2 waves/SIMD,
//    the grid itself capped occupancy). Now 8 blocks/CU; with
//    launch_bounds(128,4) forcing VGPR<=128 -> 4 waves/SIMD = 2x
//    the latency-hiding TLP; per-wave inner loop unchanged.
//  - XCD-grouping swizzle (T1, mechanism-matched): the 16 q-blocks
//    sharing one (b,kh) K/V chunk previously round-robined across
//    all 8 XCDs (each XCD L2 pulled its own copy -> FETCH 17.5 MB
//    vs ~6 ideal). bid -> g=(bid&7)+8*(bid>>7), qb=(bid>>3)&15
//    (bijective) pins all sharers of a group to one XCD.
// ---------------------------------------------------------------
__global__ __launch_bounds__(128, 4)
void attn_kernel(const half_t* __restrict__ Qh, const half_t* __restrict__ Kh,
                 const half_t* __restrict__ Vt,
                 half_t* __restrict__ Opart, float* __restrict__ lpart)
{
    __shared__ __align__(16) half_t ks[2][64 * 64];   // 2 x 8 KB [kk][h] swizzled

    const int tid = threadIdx.x;
    const int w = tid >> 6;
    const int lane = tid & 63;
    const int l15 = lane & 15;
    const int quad = lane >> 4;
    // XCD-grouping decode: all 16 qb-blocks of group g land on XCD g&7
    const int bid = blockIdx.x;
    const int g  = (bid & 7) | ((bid >> 7) << 3);   // 0..127 = (kh,b)
    const int qb = (bid >> 3) & 15;
    const int b  = g & 7;
    const int kh = g >> 3;                           // 0..15
    const int q0 = qb * 128 + w * 64;
    const int kk_begin = kh * KCHUNK;

    const half_t* Kb = Kh + (size_t)b * SEQ * HS;
    const half_t* Vb = Vt + (size_t)b * HS * SEQ;

    // stage K tile into buf p: swizzle key = (r&3)|((r>>1)&4)
    auto stage = [&](int p, int kk0) {
#pragma unroll
        for (int i = 0; i < 4; ++i) {
            int idx = i * 128 + tid;
            int r = idx >> 3, sc = idx & 7;
            int key = (r & 3) | ((r >> 1) & 4);
            int cg = sc ^ key;
            gl_lds16(Kb + (size_t)(kk0 + r) * HS + cg * 8, &ks[p][idx * 8]);
        }
    };

    stage(0, kk_begin);                    // K tile 0 in flight first

    half8 qf[4][2];
#pragma unroll
    for (int mt = 0; mt < 4; ++mt)
#pragma unroll
        for (int hst = 0; hst < 2; ++hst)
            qf[mt][hst] = *(const half8*)(Qh + ((size_t)b * SEQ + q0 + mt * 16 + l15) * HS
                                          + hst * 32 + quad * 8);

    floatx4 oacc[4][4];
    float lsum[4];                         // per-lane: q = mt*16 + l15
#pragma unroll
    for (int mt = 0; mt < 4; ++mt) {
#pragma unroll
        for (int nt = 0; nt < 4; ++nt) oacc[mt][nt] = (floatx4){0.f, 0.f, 0.f, 0.f};
        lsum[mt] = 0.f;
    }

    for (int it = 0; it < KCHUNK / 64; ++it) {
        const int cur = it & 1;
        const int kk0 = kk_begin + it * 64;
        waitcnt_all();     // this thread's async K writes landed
        __syncthreads();   // tile visible; WAR fence for buf cur^1
        if (it + 1 < KCHUNK / 64)
            stage(cur ^ 1, kk0 + 64);      // next K tile flies under compute

        // V-fragments direct from global (L2-hit), issued early so the
        // QK^T + softmax phase hides their latency
        half8 vf[4][2];
#pragma unroll
        for (int nt = 0; nt < 4; ++nt)
#pragma unroll
            for (int kst = 0; kst < 2; ++kst)
                vf[nt][kst] = *(const half8*)(Vb + (size_t)(nt * 16 + l15) * SEQ
                                              + kk0 + kst * 32 + quad * 8);

        // K fragments with sigma row remap (shared by both q-halves)
        half8 kfr[4][2];
#pragma unroll
        for (int t = 0; t < 4; ++t) {
            int r = ((t >> 1) << 5) | ((l15 >> 2) << 3) | ((t & 1) << 2) | (l15 & 3);
            int key = (r & 3) | ((r >> 1) & 4);
#pragma unroll
            for (int hst = 0; hst < 2; ++hst) {
                int slot = (hst * 4 + quad) ^ key;
                kfr[t][hst] = *(const half8*)&ks[cur][r * 64 + slot * 8];
            }
        }

#pragma unroll
        for (int h2 = 0; h2 < 2; ++h2) {
            // swapped QK^T: sacc[mtl][t][r] = P[kk = (t>>1)*32 + quad*8
            //   + (t&1)*4 + r][q = (h2*2+mtl)*16 + l15]
            floatx4 sacc[2][4];
#pragma unroll
            for (int mtl = 0; mtl < 2; ++mtl)
#pragma unroll
                for (int t = 0; t < 4; ++t) sacc[mtl][t] = (floatx4){0.f, 0.f, 0.f, 0.f};
#pragma unroll
            for (int t = 0; t < 4; ++t)
#pragma unroll
                for (int hst = 0; hst < 2; ++hst)
#pragma unroll
                    for (int mtl = 0; mtl < 2; ++mtl)
                        sacc[mtl][t] = __builtin_amdgcn_mfma_f32_16x16x32_f16(
                            kfr[t][hst], qf[h2 * 2 + mtl][hst], sacc[mtl][t], 0, 0, 0);

#pragma unroll
            for (int mtl = 0; mtl < 2; ++mtl) {
                int mt = h2 * 2 + mtl;
                // exp2 + in-lane lsum + pack: pa[kst].i[u*2+pr] holds
                // kk-pair kst*32 + quad*8 + u*4 + 2*pr — exactly the PV
                // A-fragment layout (row=q=l15, k=quad*8+j).
                union { int i[4]; half8 h; } pa[2];
#pragma unroll
                for (int t = 0; t < 4; ++t)
#pragma unroll
                    for (int pr = 0; pr < 2; ++pr) {
                        float p0 = fast_exp2(sacc[mtl][t][pr * 2]);
                        float p1 = fast_exp2(sacc[mtl][t][pr * 2 + 1]);
                        lsum[mt] += p0 + p1;
                        union { _Float16 hh[2]; int ii; } u;
                        u.hh[0] = (half_t)p0;
                        u.hh[1] = (half_t)p1;
                        pa[t >> 1].i[(t & 1) * 2 + pr] = u.ii;
                    }
#pragma unroll
                for (int kst = 0; kst < 2; ++kst)
#pragma unroll
                    for (int nt = 0; nt < 4; ++nt)
                        oacc[mt][nt] = __builtin_amdgcn_mfma_f32_16x16x32_f16(
                            pa[kst].h, vf[nt][kst], oacc[mt][nt], 0, 0, 0);
            }
        }
    }

    // reduce lsum across the 4 quads (same l15 = same q row)
#pragma unroll
    for (int mt = 0; mt < 4; ++mt) {
        float s = lsum[mt];
        s += __shfl_xor(s, 16);
        s += __shfl_xor(s, 32);
        lsum[mt] = s;
    }

    size_t obase = ((size_t)kh * BATCH + b) * SEQ * HS;
#pragma unroll
    for (int mt = 0; mt < 4; ++mt)
#pragma unroll
        for (int nt = 0; nt < 4; ++nt)
#pragma unroll
            for (int r = 0; r < 4; ++r) {
                int row = q0 + mt * 16 + quad * 4 + r;
                Opart[obase + (size_t)row * HS + nt * 16 + l15] = (half_t)oacc[mt][nt][r];
            }
    if (lane < 16) {
#pragma unroll
        for (int mt = 0; mt < 4; ++mt) {
            int row = q0 + mt * 16 + l15;
            lpart[((size_t)kh * BATCH + b) * SEQ + row] = lsum[mt];
        }
    }
}

// ---------------------------------------------------------------
// Kernel 4: combine KSPLIT partials: out = sum(O_i) / sum(l_i)
// ---------------------------------------------------------------
__global__ __launch_bounds__(256)
void combine_kernel(const half_t* __restrict__ Opart, const float* __restrict__ lpart,
                    float* __restrict__ out)
{
    const size_t NT = (size_t)BATCH * SEQ * HS;
    const size_t BS = (size_t)BATCH * SEQ;
    size_t e0 = ((size_t)blockIdx.x * 256 + threadIdx.x) * 8;
    size_t row = e0 / HS;
    float o[8] = {0, 0, 0, 0, 0, 0, 0, 0};
    float l = 0.f;
#pragma unroll
    for (int i = 0; i < KSPLIT; ++i) {
        half8 oi = *(const half8*)(Opart + (size_t)i * NT + e0);
#pragma unroll
        for (int j = 0; j < 8; ++j) o[j] += (float)oi[j];
        l += lpart[(size_t)i * BS + row];
    }
    float inv = 1.f / l;
    float4 a = {o[0] * inv, o[1] * inv, o[2] * inv, o[3] * inv};
    float4 c = {o[4] * inv, o[5] * inv, o[6] * inv, o[7] * inv};
    *(float4*)(out + e0) = a;
    *(float4*)(out + e0 + 4) = c;
}

extern "C" void kernel_launch(void* const* d_in, const int* in_sizes, int n_in,
                              void* d_out, int out_size, void* d_ws, size_t ws_size,
                              hipStream_t stream) {
    const float* x  = (const float*)d_in[0];
    const float* Wq = (const float*)d_in[1];
    const float* bq = (const float*)d_in[2];
    const float* Wk = (const float*)d_in[3];
    const float* bk = (const float*)d_in[4];
    const float* Wv = (const float*)d_in[5];
    const float* bv = (const float*)d_in[6];
    float* out = (float*)d_out;

    const size_t per = (size_t)BATCH * SEQ * HS;      // 1,048,576 elements
    half_t* Qh = (half_t*)d_ws;
    half_t* Kh = Qh + per;
    half_t* Vt = Kh + per;
    half_t* Wt = Vt + per;                            // 147,456 halfs
    half_t* Opart = Wt + 3 * HS * D_MODEL;
    float*  lpart = (float*)(Opart + (size_t)KSPLIT * per);   // ~40 MB total

    wconv_kernel<<<dim3(36), dim3(256), 0, stream>>>(Wq, Wk, Wv, Wt);
    proj_kernel<<<dim3(BATCH * SEQ / PM), dim3(256), 0, stream>>>(
        x, Wt, bq, bk, bv, Qh, Kh, Vt);
    attn_kernel<<<dim3((SEQ / 128) * BATCH * KSPLIT), dim3(128), 0, stream>>>(
        Qh, Kh, Vt, Opart, lpart);
    combine_kernel<<<dim3((BATCH * SEQ * HS) / (256 * 8)), dim3(256), 0, stream>>>(
        Opart, lpart, out);
}

// Round 13
// 133.017 us; speedup vs baseline: 1.2728x; 1.2728x over previous
//
#include <hip/hip_runtime.h>
#include <math.h>

#define D_MODEL 768
#define HS 64
#define BATCH 8
#define SEQ 2048
// Q is pre-scaled by 0.125*log2(e) in proj's epilogue (fp32), so attn
// computes P = 2^(Qs . K) with a single v_exp_f32 and no extra muls.
#define QSCALE_LOG2E 0.1803368801f
#define KSPLIT 8
#define KCHUNK (SEQ / KSPLIT)   // 256
#define PM 32                   // proj M-tile -> grid 512

typedef _Float16 half_t;
typedef __attribute__((ext_vector_type(8))) _Float16 half8;
typedef __attribute__((ext_vector_type(4))) float floatx4;

// async global->LDS, 16B per lane, lane-linear LDS destination
typedef const __attribute__((address_space(1))) void gas_void;
typedef __attribute__((address_space(3))) void las_void;
__device__ __forceinline__ void gl_lds16(const void* g, void* l) {
    __builtin_amdgcn_global_load_lds((gas_void*)g, (las_void*)l, 16, 0, 0);
}
__device__ __forceinline__ void waitcnt_all() {
    __builtin_amdgcn_s_waitcnt(0);
}
__device__ __forceinline__ float fast_exp2(float x) {
#if __has_builtin(__builtin_amdgcn_exp2f)
    return __builtin_amdgcn_exp2f(x);
#else
    return exp2f(x);
#endif
}

// ---------------------------------------------------------------
// Kernel 1: W fp32 [D][H] x3 -> Wt fp16 [3*H][D], via coalesced
// 64x64 LDS transpose. Grid 36 = 3 matrices x 12 k-tiles.
// ---------------------------------------------------------------
__global__ __launch_bounds__(256)
void wconv_kernel(const float* __restrict__ Wq, const float* __restrict__ Wk,
                  const float* __restrict__ Wv, half_t* __restrict__ Wt)
{
    __shared__ float lds[64][65];
    const int m = blockIdx.x / 12;
    const int k0 = (blockIdx.x % 12) * 64;
    const float* W = (m == 0) ? Wq : ((m == 1) ? Wk : Wv);
    const int tid = threadIdx.x;
#pragma unroll
    for (int ri = 0; ri < 4; ++ri) {
        int row = ri * 16 + (tid >> 4);
        int col = (tid & 15) * 4;
        float4 v = *(const float4*)(W + (size_t)(k0 + row) * HS + col);
        lds[row][col] = v.x; lds[row][col + 1] = v.y;
        lds[row][col + 2] = v.z; lds[row][col + 3] = v.w;
    }
    __syncthreads();
#pragma unroll
    for (int i = 0; i < 2; ++i) {
        int idx = i * 256 + tid;
        int h = idx >> 3;
        int kc = idx & 7;
        half8 o;
#pragma unroll
        for (int j = 0; j < 8; ++j) o[j] = (half_t)lds[kc * 8 + j][h];
        *(half8*)(Wt + (size_t)(m * HS + h) * D_MODEL + k0 + kc * 8) = o;
    }
}

// ---------------------------------------------------------------
// Kernel 2: QKV projection (R9, unchanged). M=32 x N=192 tile,
// parity dbuf LDS, W staging via global_load_lds.
// ---------------------------------------------------------------
__global__ __launch_bounds__(256)
void proj_kernel(const float* __restrict__ x, const half_t* __restrict__ Wt,
                 const float* __restrict__ bq, const float* __restrict__ bk,
                 const float* __restrict__ bv,
                 half_t* __restrict__ Qh, half_t* __restrict__ Kh,
                 half_t* __restrict__ Vt)
{
    __shared__ __align__(16) half_t xs[2][PM * 64];    // 2 x 4 KB
    __shared__ __align__(16) half_t wtl[2][192 * 64];  // 2 x 24 KB

    const int tid = threadIdx.x;
    const int w = tid >> 6;
    const int lane = tid & 63;
    const int l15 = lane & 15;
    const int quad = lane >> 4;
    const long row0 = (long)blockIdx.x * PM;

    floatx4 acc[2][3];
#pragma unroll
    for (int i = 0; i < 2; ++i)
#pragma unroll
        for (int j = 0; j < 3; ++j) acc[i][j] = (floatx4){0.f, 0.f, 0.f, 0.f};

    float4 xA[2], xB[2];

    auto loadx = [&](int k0, float4 (&v)[2]) {
        int r = tid >> 3, sc = tid & 7;
        int cg = sc ^ (r & 7);
        const float* p = x + (row0 + r) * D_MODEL + k0 + cg * 8;
        v[0] = *(const float4*)p;
        v[1] = *(const float4*)(p + 4);
    };
    // async W stage: same global pre-swizzle, lane-linear LDS dest
    auto stage_w = [&](int p, int k0) {
#pragma unroll
        for (int i = 0; i < 6; ++i) {
            int idx = i * 256 + tid;
            int r = idx >> 3, sc = idx & 7;
            int cg = sc ^ (r & 7);
            gl_lds16(Wt + (size_t)r * D_MODEL + k0 + cg * 8, &wtl[p][idx * 8]);
        }
    };

    auto step = [&](int it, float4 (&xc)[2], float4 (&xn)[2], int p) {
        {
            float4 a = xc[0], b = xc[1];
            half8 xh = (half8){(half_t)a.x, (half_t)a.y, (half_t)a.z, (half_t)a.w,
                               (half_t)b.x, (half_t)b.y, (half_t)b.z, (half_t)b.w};
            *(half8*)&xs[p][tid * 8] = xh;
        }
        waitcnt_all();                   // this wave's W gl_lds (tile it) landed
        __syncthreads();                 // xs[p]+wtl[p] visible to all waves
        int kn = (it + 1 < 12) ? (it + 1) * 64 : 0;
        if (it + 1 < 12) stage_w(p ^ 1, kn);
        loadx(kn, xn);
#pragma unroll
        for (int kst = 0; kst < 2; ++kst) {
            half8 af[2];
#pragma unroll
            for (int mt = 0; mt < 2; ++mt) {
                int r = mt * 16 + l15;
                int slot = (kst * 4 + quad) ^ (r & 7);
                af[mt] = *(const half8*)&xs[p][r * 64 + slot * 8];
            }
#pragma unroll
            for (int nt = 0; nt < 3; ++nt) {
                int r = w * 48 + nt * 16 + l15;
                int slot = (kst * 4 + quad) ^ (r & 7);
                half8 bf = *(const half8*)&wtl[p][r * 64 + slot * 8];
#pragma unroll
                for (int mt = 0; mt < 2; ++mt)
                    acc[mt][nt] = __builtin_amdgcn_mfma_f32_16x16x32_f16(
                        af[mt], bf, acc[mt][nt], 0, 0, 0);
            }
        }
    };

    stage_w(0, 0);                       // W tile 0 in flight
    loadx(0, xA);
#pragma unroll
    for (int it = 0; it < 12; it += 2) {
        step(it,     xA, xB, 0);
        step(it + 1, xB, xA, 1);
    }

    // epilogue: bias (+ Q pre-scale) + fp16 store
#pragma unroll
    for (int nt = 0; nt < 3; ++nt) {
        int nbase = w * 48 + nt * 16;
        int mm = nbase >> 6;
        int h = (nbase + l15) & 63;
        const float* bias = (mm == 0) ? bq : ((mm == 1) ? bk : bv);
        float bval = bias[h];
#pragma unroll
        for (int mt = 0; mt < 2; ++mt)
#pragma unroll
            for (int r = 0; r < 4; ++r) {
                long R = row0 + mt * 16 + quad * 4 + r;
                float fv = acc[mt][nt][r] + bval;
                if (mm == 0) {
                    Qh[R * HS + h] = (half_t)(fv * QSCALE_LOG2E);
                } else if (mm == 1) {
                    Kh[R * HS + h] = (half_t)fv;
                } else {
                    long bb = R >> 11, s = R & 2047;
                    Vt[(bb * HS + h) * SEQ + s] = (half_t)fv;
                }
            }
    }
}

// ---------------------------------------------------------------
// Kernel 3: flash attention. EXACT R9 interior (132.8 µs best),
// KSPLIT=8, plain launch_bounds(128) — R10's (128,4) forced VGPR
// 136->64 and spilled (WRITE 16.9->152 MB, the regression).
// ONE change vs R9: XCD-grouping bid swizzle (T1). Grid 1024 =
// 16 qb x 64 (b,kh) groups; g=(bid&7)|((bid>>7)<<3), qb=(bid>>3)&15
// (bijective: bid=(g&7)+8*qb+128*(g>>3)). All 16 q-blocks sharing
// one (b,kh) K/V chunk have the same bid&7 -> same XCD -> chunk is
// fetched into ONE XCD L2 instead of all eight (FETCH 17.5 MB vs
// ~6 ideal was the round-robin signature).
// ---------------------------------------------------------------
__global__ __launch_bounds__(128)
void attn_kernel(const half_t* __restrict__ Qh, const half_t* __restrict__ Kh,
                 const half_t* __restrict__ Vt,
                 half_t* __restrict__ Opart, float* __restrict__ lpart)
{
    __shared__ __align__(16) half_t ks[2][64 * 64];   // 2 x 8 KB [kk][h] swizzled

    const int tid = threadIdx.x;
    const int w = tid >> 6;
    const int lane = tid & 63;
    const int l15 = lane & 15;
    const int quad = lane >> 4;
    // XCD-grouping decode
    const int bid = blockIdx.x;
    const int g  = (bid & 7) | ((bid >> 7) << 3);    // 0..63 = (b,kh)
    const int qb = (bid >> 3) & 15;
    const int b  = g & 7;
    const int kh = g >> 3;                           // 0..7
    const int q0 = qb * 128 + w * 64;
    const int kk_begin = kh * KCHUNK;

    const half_t* Kb = Kh + (size_t)b * SEQ * HS;
    const half_t* Vb = Vt + (size_t)b * HS * SEQ;

    // stage K tile into buf p: swizzle key = (r&3)|((r>>1)&4)
    auto stage = [&](int p, int kk0) {
#pragma unroll
        for (int i = 0; i < 4; ++i) {
            int idx = i * 128 + tid;
            int r = idx >> 3, sc = idx & 7;
            int key = (r & 3) | ((r >> 1) & 4);
            int cg = sc ^ key;
            gl_lds16(Kb + (size_t)(kk0 + r) * HS + cg * 8, &ks[p][idx * 8]);
        }
    };

    stage(0, kk_begin);                    // K tile 0 in flight first

    half8 qf[4][2];
#pragma unroll
    for (int mt = 0; mt < 4; ++mt)
#pragma unroll
        for (int hst = 0; hst < 2; ++hst)
            qf[mt][hst] = *(const half8*)(Qh + ((size_t)b * SEQ + q0 + mt * 16 + l15) * HS
                                          + hst * 32 + quad * 8);

    floatx4 oacc[4][4];
    float lsum[4];                         // per-lane: q = mt*16 + l15
#pragma unroll
    for (int mt = 0; mt < 4; ++mt) {
#pragma unroll
        for (int nt = 0; nt < 4; ++nt) oacc[mt][nt] = (floatx4){0.f, 0.f, 0.f, 0.f};
        lsum[mt] = 0.f;
    }

    for (int it = 0; it < KCHUNK / 64; ++it) {
        const int cur = it & 1;
        const int kk0 = kk_begin + it * 64;
        waitcnt_all();     // this thread's async K writes landed
        __syncthreads();   // tile visible; WAR fence for buf cur^1
        if (it + 1 < KCHUNK / 64)
            stage(cur ^ 1, kk0 + 64);      // next K tile flies under compute

        // V-fragments direct from global (L2-hit), issued early so the
        // QK^T + softmax phase hides their latency
        half8 vf[4][2];
#pragma unroll
        for (int nt = 0; nt < 4; ++nt)
#pragma unroll
            for (int kst = 0; kst < 2; ++kst)
                vf[nt][kst] = *(const half8*)(Vb + (size_t)(nt * 16 + l15) * SEQ
                                              + kk0 + kst * 32 + quad * 8);

        // K fragments with sigma row remap (shared by both q-halves)
        half8 kfr[4][2];
#pragma unroll
        for (int t = 0; t < 4; ++t) {
            int r = ((t >> 1) << 5) | ((l15 >> 2) << 3) | ((t & 1) << 2) | (l15 & 3);
            int key = (r & 3) | ((r >> 1) & 4);
#pragma unroll
            for (int hst = 0; hst < 2; ++hst) {
                int slot = (hst * 4 + quad) ^ key;
                kfr[t][hst] = *(const half8*)&ks[cur][r * 64 + slot * 8];
            }
        }

#pragma unroll
        for (int h2 = 0; h2 < 2; ++h2) {
            // swapped QK^T: sacc[mtl][t][r] = P[kk = (t>>1)*32 + quad*8
            //   + (t&1)*4 + r][q = (h2*2+mtl)*16 + l15]
            floatx4 sacc[2][4];
#pragma unroll
            for (int mtl = 0; mtl < 2; ++mtl)
#pragma unroll
                for (int t = 0; t < 4; ++t) sacc[mtl][t] = (floatx4){0.f, 0.f, 0.f, 0.f};
#pragma unroll
            for (int t = 0; t < 4; ++t)
#pragma unroll
                for (int hst = 0; hst < 2; ++hst)
#pragma unroll
                    for (int mtl = 0; mtl < 2; ++mtl)
                        sacc[mtl][t] = __builtin_amdgcn_mfma_f32_16x16x32_f16(
                            kfr[t][hst], qf[h2 * 2 + mtl][hst], sacc[mtl][t], 0, 0, 0);

#pragma unroll
            for (int mtl = 0; mtl < 2; ++mtl) {
                int mt = h2 * 2 + mtl;
                // exp2 + in-lane lsum + pack: pa[kst].i[u*2+pr] holds
                // kk-pair kst*32 + quad*8 + u*4 + 2*pr — exactly the PV
                // A-fragment layout (row=q=l15, k=quad*8+j).
                union { int i[4]; half8 h; } pa[2];
#pragma unroll
                for (int t = 0; t < 4; ++t)
#pragma unroll
                    for (int pr = 0; pr < 2; ++pr) {
                        float p0 = fast_exp2(sacc[mtl][t][pr * 2]);
                        float p1 = fast_exp2(sacc[mtl][t][pr * 2 + 1]);
                        lsum[mt] += p0 + p1;
                        union { _Float16 hh[2]; int ii; } u;
                        u.hh[0] = (half_t)p0;
                        u.hh[1] = (half_t)p1;
                        pa[t >> 1].i[(t & 1) * 2 + pr] = u.ii;
                    }
#pragma unroll
                for (int kst = 0; kst < 2; ++kst)
#pragma unroll
                    for (int nt = 0; nt < 4; ++nt)
                        oacc[mt][nt] = __builtin_amdgcn_mfma_f32_16x16x32_f16(
                            pa[kst].h, vf[nt][kst], oacc[mt][nt], 0, 0, 0);
            }
        }
    }

    // reduce lsum across the 4 quads (same l15 = same q row)
#pragma unroll
    for (int mt = 0; mt < 4; ++mt) {
        float s = lsum[mt];
        s += __shfl_xor(s, 16);
        s += __shfl_xor(s, 32);
        lsum[mt] = s;
    }

    size_t obase = ((size_t)kh * BATCH + b) * SEQ * HS;
#pragma unroll
    for (int mt = 0; mt < 4; ++mt)
#pragma unroll
        for (int nt = 0; nt < 4; ++nt)
#pragma unroll
            for (int r = 0; r < 4; ++r) {
                int row = q0 + mt * 16 + quad * 4 + r;
                Opart[obase + (size_t)row * HS + nt * 16 + l15] = (half_t)oacc[mt][nt][r];
            }
    if (lane < 16) {
#pragma unroll
        for (int mt = 0; mt < 4; ++mt) {
            int row = q0 + mt * 16 + l15;
            lpart[((size_t)kh * BATCH + b) * SEQ + row] = lsum[mt];
        }
    }
}

// ---------------------------------------------------------------
// Kernel 4: combine KSPLIT partials: out = sum(O_i) / sum(l_i)
// ---------------------------------------------------------------
__global__ __launch_bounds__(256)
void combine_kernel(const half_t* __restrict__ Opart, const float* __restrict__ lpart,
                    float* __restrict__ out)
{
    const size_t NT = (size_t)BATCH * SEQ * HS;
    const size_t BS = (size_t)BATCH * SEQ;
    size_t e0 = ((size_t)blockIdx.x * 256 + threadIdx.x) * 8;
    size_t row = e0 / HS;
    float o[8] = {0, 0, 0, 0, 0, 0, 0, 0};
    float l = 0.f;
#pragma unroll
    for (int i = 0; i < KSPLIT; ++i) {
        half8 oi = *(const half8*)(Opart + (size_t)i * NT + e0);
#pragma unroll
        for (int j = 0; j < 8; ++j) o[j] += (float)oi[j];
        l += lpart[(size_t)i * BS + row];
    }
    float inv = 1.f / l;
    float4 a = {o[0] * inv, o[1] * inv, o[2] * inv, o[3] * inv};
    float4 c = {o[4] * inv, o[5] * inv, o[6] * inv, o[7] * inv};
    *(float4*)(out + e0) = a;
    *(float4*)(out + e0 + 4) = c;
}

extern "C" void kernel_launch(void* const* d_in, const int* in_sizes, int n_in,
                              void* d_out, int out_size, void* d_ws, size_t ws_size,
                              hipStream_t stream) {
    const float* x  = (const float*)d_in[0];
    const float* Wq = (const float*)d_in[1];
    const float* bq = (const float*)d_in[2];
    const float* Wk = (const float*)d_in[3];
    const float* bk = (const float*)d_in[4];
    const float* Wv = (const float*)d_in[5];
    const float* bv = (const float*)d_in[6];
    float* out = (float*)d_out;

    const size_t per = (size_t)BATCH * SEQ * HS;      // 1,048,576 elements
    half_t* Qh = (half_t*)d_ws;
    half_t* Kh = Qh + per;
    half_t* Vt = Kh + per;
    half_t* Wt = Vt + per;                            // 147,456 halfs
    half_t* Opart = Wt + 3 * HS * D_MODEL;
    float*  lpart = (float*)(Opart + (size_t)KSPLIT * per);   // ~23 MB total

    wconv_kernel<<<dim3(36), dim3(256), 0, stream>>>(Wq, Wk, Wv, Wt);
    proj_kernel<<<dim3(BATCH * SEQ / PM), dim3(256), 0, stream>>>(
        x, Wt, bq, bk, bv, Qh, Kh, Vt);
    attn_kernel<<<dim3((SEQ / 128) * BATCH * KSPLIT), dim3(128), 0, stream>>>(
        Qh, Kh, Vt, Opart, lpart);
    combine_kernel<<<dim3((BATCH * SEQ * HS) / (256 * 8)), dim3(256), 0, stream>>>(
        Opart, lpart, out);
}

// Round 14
// 125.808 us; speedup vs baseline: 1.3457x; 1.0573x over previous
//
#include <hip/hip_runtime.h>
#include <math.h>

#define D_MODEL 768
#define HS 64
#define BATCH 8
#define SEQ 2048
// Q is pre-scaled by 0.125*log2(e) in proj's epilogue (fp32), so attn
// computes P = 2^(Qs . K) with a single v_exp_f32 and no extra muls.
#define QSCALE_LOG2E 0.1803368801f
#define KSPLIT 8
#define KCHUNK (SEQ / KSPLIT)   // 256 kk per wave
#define PM 32                   // proj M-tile -> grid 512

typedef _Float16 half_t;
typedef __attribute__((ext_vector_type(8))) _Float16 half8;
typedef __attribute__((ext_vector_type(4))) float floatx4;

// async global->LDS, 16B per lane, lane-linear LDS destination
typedef const __attribute__((address_space(1))) void gas_void;
typedef __attribute__((address_space(3))) void las_void;
__device__ __forceinline__ void gl_lds16(const void* g, void* l) {
    __builtin_amdgcn_global_load_lds((gas_void*)g, (las_void*)l, 16, 0, 0);
}
__device__ __forceinline__ void waitcnt_all() {
    __builtin_amdgcn_s_waitcnt(0);
}
__device__ __forceinline__ float fast_exp2(float x) {
#if __has_builtin(__builtin_amdgcn_exp2f)
    return __builtin_amdgcn_exp2f(x);
#else
    return exp2f(x);
#endif
}

// ---------------------------------------------------------------
// Kernel 1: W fp32 [D][H] x3 -> Wt fp16 [3*H][D], via coalesced
// 64x64 LDS transpose. Grid 36 = 3 matrices x 12 k-tiles.
// ---------------------------------------------------------------
__global__ __launch_bounds__(256)
void wconv_kernel(const float* __restrict__ Wq, const float* __restrict__ Wk,
                  const float* __restrict__ Wv, half_t* __restrict__ Wt)
{
    __shared__ float lds[64][65];
    const int m = blockIdx.x / 12;
    const int k0 = (blockIdx.x % 12) * 64;
    const float* W = (m == 0) ? Wq : ((m == 1) ? Wk : Wv);
    const int tid = threadIdx.x;
#pragma unroll
    for (int ri = 0; ri < 4; ++ri) {
        int row = ri * 16 + (tid >> 4);
        int col = (tid & 15) * 4;
        float4 v = *(const float4*)(W + (size_t)(k0 + row) * HS + col);
        lds[row][col] = v.x; lds[row][col + 1] = v.y;
        lds[row][col + 2] = v.z; lds[row][col + 3] = v.w;
    }
    __syncthreads();
#pragma unroll
    for (int i = 0; i < 2; ++i) {
        int idx = i * 256 + tid;
        int h = idx >> 3;
        int kc = idx & 7;
        half8 o;
#pragma unroll
        for (int j = 0; j < 8; ++j) o[j] = (half_t)lds[kc * 8 + j][h];
        *(half8*)(Wt + (size_t)(m * HS + h) * D_MODEL + k0 + kc * 8) = o;
    }
}

// ---------------------------------------------------------------
// Kernel 2: QKV projection (R9, unchanged). M=32 x N=192 tile,
// parity dbuf LDS, W staging via global_load_lds.
// ---------------------------------------------------------------
__global__ __launch_bounds__(256)
void proj_kernel(const float* __restrict__ x, const half_t* __restrict__ Wt,
                 const float* __restrict__ bq, const float* __restrict__ bk,
                 const float* __restrict__ bv,
                 half_t* __restrict__ Qh, half_t* __restrict__ Kh,
                 half_t* __restrict__ Vt)
{
    __shared__ __align__(16) half_t xs[2][PM * 64];    // 2 x 4 KB
    __shared__ __align__(16) half_t wtl[2][192 * 64];  // 2 x 24 KB

    const int tid = threadIdx.x;
    const int w = tid >> 6;
    const int lane = tid & 63;
    const int l15 = lane & 15;
    const int quad = lane >> 4;
    const long row0 = (long)blockIdx.x * PM;

    floatx4 acc[2][3];
#pragma unroll
    for (int i = 0; i < 2; ++i)
#pragma unroll
        for (int j = 0; j < 3; ++j) acc[i][j] = (floatx4){0.f, 0.f, 0.f, 0.f};

    float4 xA[2], xB[2];

    auto loadx = [&](int k0, float4 (&v)[2]) {
        int r = tid >> 3, sc = tid & 7;
        int cg = sc ^ (r & 7);
        const float* p = x + (row0 + r) * D_MODEL + k0 + cg * 8;
        v[0] = *(const float4*)p;
        v[1] = *(const float4*)(p + 4);
    };
    // async W stage: same global pre-swizzle, lane-linear LDS dest
    auto stage_w = [&](int p, int k0) {
#pragma unroll
        for (int i = 0; i < 6; ++i) {
            int idx = i * 256 + tid;
            int r = idx >> 3, sc = idx & 7;
            int cg = sc ^ (r & 7);
            gl_lds16(Wt + (size_t)r * D_MODEL + k0 + cg * 8, &wtl[p][idx * 8]);
        }
    };

    auto step = [&](int it, float4 (&xc)[2], float4 (&xn)[2], int p) {
        {
            float4 a = xc[0], b = xc[1];
            half8 xh = (half8){(half_t)a.x, (half_t)a.y, (half_t)a.z, (half_t)a.w,
                               (half_t)b.x, (half_t)b.y, (half_t)b.z, (half_t)b.w};
            *(half8*)&xs[p][tid * 8] = xh;
        }
        waitcnt_all();                   // this wave's W gl_lds (tile it) landed
        __syncthreads();                 // xs[p]+wtl[p] visible to all waves
        int kn = (it + 1 < 12) ? (it + 1) * 64 : 0;
        if (it + 1 < 12) stage_w(p ^ 1, kn);
        loadx(kn, xn);
#pragma unroll
        for (int kst = 0; kst < 2; ++kst) {
            half8 af[2];
#pragma unroll
            for (int mt = 0; mt < 2; ++mt) {
                int r = mt * 16 + l15;
                int slot = (kst * 4 + quad) ^ (r & 7);
                af[mt] = *(const half8*)&xs[p][r * 64 + slot * 8];
            }
#pragma unroll
            for (int nt = 0; nt < 3; ++nt) {
                int r = w * 48 + nt * 16 + l15;
                int slot = (kst * 4 + quad) ^ (r & 7);
                half8 bf = *(const half8*)&wtl[p][r * 64 + slot * 8];
#pragma unroll
                for (int mt = 0; mt < 2; ++mt)
                    acc[mt][nt] = __builtin_amdgcn_mfma_f32_16x16x32_f16(
                        af[mt], bf, acc[mt][nt], 0, 0, 0);
            }
        }
    };

    stage_w(0, 0);                       // W tile 0 in flight
    loadx(0, xA);
#pragma unroll
    for (int it = 0; it < 12; it += 2) {
        step(it,     xA, xB, 0);
        step(it + 1, xB, xA, 1);
    }

    // epilogue: bias (+ Q pre-scale) + fp16 store
#pragma unroll
    for (int nt = 0; nt < 3; ++nt) {
        int nbase = w * 48 + nt * 16;
        int mm = nbase >> 6;
        int h = (nbase + l15) & 63;
        const float* bias = (mm == 0) ? bq : ((mm == 1) ? bk : bv);
        float bval = bias[h];
#pragma unroll
        for (int mt = 0; mt < 2; ++mt)
#pragma unroll
            for (int r = 0; r < 4; ++r) {
                long R = row0 + mt * 16 + quad * 4 + r;
                float fv = acc[mt][nt][r] + bval;
                if (mm == 0) {
                    Qh[R * HS + h] = (half_t)(fv * QSCALE_LOG2E);
                } else if (mm == 1) {
                    Kh[R * HS + h] = (half_t)fv;
                } else {
                    long bb = R >> 11, s = R & 2047;
                    Vt[(bb * HS + h) * SEQ + s] = (half_t)fv;
                }
            }
    }
}

// ---------------------------------------------------------------
// Kernel 3: flash attention + in-block combine. 8-wave blocks
// (512 thr); block = (b, 64-q-row tile), wave w = kh chunk w
// (256 kk each, 4 x 64-kk tiles). K and V read DIRECT from global
// (both L2-resident; m169 validated this for V, K is symmetric):
// the main loop has ZERO LDS, ZERO barriers, ZERO waitcnt — the
// compiler pipelines loads across tiles freely. Wave interior
// math byte-identical to R13 (sigma remap, swapped QK^T, packed
// exp2 = PV A-frag). Epilogue: fp16 partial O slices (same
// precision as the old Opart) + f32 lsum into 68 KB LDS, one
// __syncthreads, 8-slice tree-sum, fp32 out written directly.
// Eliminates the combine kernel + its 36 MB HBM round-trip, with
// no cross-block communication (no G16 risk).
// ---------------------------------------------------------------
__global__ __launch_bounds__(512)
void attn8_kernel(const half_t* __restrict__ Qh, const half_t* __restrict__ Kh,
                  const half_t* __restrict__ Vt, float* __restrict__ out)
{
    __shared__ __align__(16) half_t osl[8][4096 + 32];   // 66 KB (pad vs aliasing)
    __shared__ float lsl[8][64];                          // 2 KB

    const int tid = threadIdx.x;
    const int w = tid >> 6;            // wave = kh chunk
    const int lane = tid & 63;
    const int l15 = lane & 15;
    const int quad = lane >> 4;
    const int b  = blockIdx.x >> 5;    // batch
    const int qt = blockIdx.x & 31;    // 64-row q tile
    const int q0 = qt * 64;
    const int kk_begin = w * KCHUNK;

    const half_t* Kb = Kh + (size_t)b * SEQ * HS;
    const half_t* Vb = Vt + (size_t)b * HS * SEQ;

    half8 qf[4][2];
#pragma unroll
    for (int mt = 0; mt < 4; ++mt)
#pragma unroll
        for (int hst = 0; hst < 2; ++hst)
            qf[mt][hst] = *(const half8*)(Qh + ((size_t)b * SEQ + q0 + mt * 16 + l15) * HS
                                          + hst * 32 + quad * 8);

    floatx4 oacc[4][4];
    float lsum[4];                     // per-lane: q = mt*16 + l15
#pragma unroll
    for (int mt = 0; mt < 4; ++mt) {
#pragma unroll
        for (int nt = 0; nt < 4; ++nt) oacc[mt][nt] = (floatx4){0.f, 0.f, 0.f, 0.f};
        lsum[mt] = 0.f;
    }

    for (int it = 0; it < KCHUNK / 64; ++it) {
        const int kk0 = kk_begin + it * 64;

        // V-fragments direct from global (L2-hit)
        half8 vf[4][2];
#pragma unroll
        for (int nt = 0; nt < 4; ++nt)
#pragma unroll
            for (int kst = 0; kst < 2; ++kst)
                vf[nt][kst] = *(const half8*)(Vb + (size_t)(nt * 16 + l15) * SEQ
                                              + kk0 + kst * 32 + quad * 8);

        // K fragments direct from global with sigma row remap
        half8 kfr[4][2];
#pragma unroll
        for (int t = 0; t < 4; ++t) {
            int r = ((t >> 1) << 5) | ((l15 >> 2) << 3) | ((t & 1) << 2) | (l15 & 3);
#pragma unroll
            for (int hst = 0; hst < 2; ++hst)
                kfr[t][hst] = *(const half8*)(Kb + (size_t)(kk0 + r) * HS
                                              + hst * 32 + quad * 8);
        }

#pragma unroll
        for (int h2 = 0; h2 < 2; ++h2) {
            // swapped QK^T: sacc[mtl][t][r] = P[kk = (t>>1)*32 + quad*8
            //   + (t&1)*4 + r][q = (h2*2+mtl)*16 + l15]
            floatx4 sacc[2][4];
#pragma unroll
            for (int mtl = 0; mtl < 2; ++mtl)
#pragma unroll
                for (int t = 0; t < 4; ++t) sacc[mtl][t] = (floatx4){0.f, 0.f, 0.f, 0.f};
#pragma unroll
            for (int t = 0; t < 4; ++t)
#pragma unroll
                for (int hst = 0; hst < 2; ++hst)
#pragma unroll
                    for (int mtl = 0; mtl < 2; ++mtl)
                        sacc[mtl][t] = __builtin_amdgcn_mfma_f32_16x16x32_f16(
                            kfr[t][hst], qf[h2 * 2 + mtl][hst], sacc[mtl][t], 0, 0, 0);

#pragma unroll
            for (int mtl = 0; mtl < 2; ++mtl) {
                int mt = h2 * 2 + mtl;
                // exp2 + in-lane lsum + pack: pa[kst].i[u*2+pr] holds
                // kk-pair kst*32 + quad*8 + u*4 + 2*pr — exactly the PV
                // A-fragment layout (row=q=l15, k=quad*8+j).
                union { int i[4]; half8 h; } pa[2];
#pragma unroll
                for (int t = 0; t < 4; ++t)
#pragma unroll
                    for (int pr = 0; pr < 2; ++pr) {
                        float p0 = fast_exp2(sacc[mtl][t][pr * 2]);
                        float p1 = fast_exp2(sacc[mtl][t][pr * 2 + 1]);
                        lsum[mt] += p0 + p1;
                        union { _Float16 hh[2]; int ii; } u;
                        u.hh[0] = (half_t)p0;
                        u.hh[1] = (half_t)p1;
                        pa[t >> 1].i[(t & 1) * 2 + pr] = u.ii;
                    }
#pragma unroll
                for (int kst = 0; kst < 2; ++kst)
#pragma unroll
                    for (int nt = 0; nt < 4; ++nt)
                        oacc[mt][nt] = __builtin_amdgcn_mfma_f32_16x16x32_f16(
                            pa[kst].h, vf[nt][kst], oacc[mt][nt], 0, 0, 0);
            }
        }
    }

    // reduce lsum across the 4 quads (same l15 = same q row)
#pragma unroll
    for (int mt = 0; mt < 4; ++mt) {
        float s = lsum[mt];
        s += __shfl_xor(s, 16);
        s += __shfl_xor(s, 32);
        lsum[mt] = s;
    }

    // deposit this wave's partial tile (fp16, same precision as old Opart)
#pragma unroll
    for (int mt = 0; mt < 4; ++mt)
#pragma unroll
        for (int nt = 0; nt < 4; ++nt)
#pragma unroll
            for (int r = 0; r < 4; ++r) {
                int row = mt * 16 + quad * 4 + r;
                osl[w][row * 64 + nt * 16 + l15] = (half_t)oacc[mt][nt][r];
            }
    if (quad == 0)
#pragma unroll
        for (int mt = 0; mt < 4; ++mt)
            lsl[w][mt * 16 + l15] = lsum[mt];
    __syncthreads();

    // in-block combine: wave w sums rows {i*8 + w}, cols = lane
#pragma unroll
    for (int i = 0; i < 8; ++i) {
        int row = i * 8 + w;
        float s = 0.f, l = 0.f;
#pragma unroll
        for (int s8 = 0; s8 < 8; ++s8) {
            s += (float)osl[s8][row * 64 + lane];
            l += lsl[s8][row];
        }
        out[((size_t)b * SEQ + q0 + row) * HS + lane] = s / l;
    }
}

extern "C" void kernel_launch(void* const* d_in, const int* in_sizes, int n_in,
                              void* d_out, int out_size, void* d_ws, size_t ws_size,
                              hipStream_t stream) {
    const float* x  = (const float*)d_in[0];
    const float* Wq = (const float*)d_in[1];
    const float* bq = (const float*)d_in[2];
    const float* Wk = (const float*)d_in[3];
    const float* bk = (const float*)d_in[4];
    const float* Wv = (const float*)d_in[5];
    const float* bv = (const float*)d_in[6];
    float* out = (float*)d_out;

    const size_t per = (size_t)BATCH * SEQ * HS;      // 1,048,576 elements
    half_t* Qh = (half_t*)d_ws;
    half_t* Kh = Qh + per;
    half_t* Vt = Kh + per;
    half_t* Wt = Vt + per;                            // 147,456 halfs

    wconv_kernel<<<dim3(36), dim3(256), 0, stream>>>(Wq, Wk, Wv, Wt);
    proj_kernel<<<dim3(BATCH * SEQ / PM), dim3(256), 0, stream>>>(
        x, Wt, bq, bk, bv, Qh, Kh, Vt);
    attn8_kernel<<<dim3(BATCH * (SEQ / 64)), dim3(512), 0, stream>>>(
        Qh, Kh, Vt, out);
}